// Round 1
// baseline (72.770 us; speedup 1.0000x reference)
//
#include <hip/hip_runtime.h>
#include <math.h>

// Rolling population std, window W=64, per row of x[B=4096][T=8192] fp32.
// out[b][j] = sqrt(max(E[x^2]-E[x]^2, 0)) over x[b][j..j+W-1], j in [0, T-W+1).
//
// Memory-bound: 128 MiB in + 127 MiB out => ~43 us floor at 6.3 TB/s.
// One 256-thread block per row; row staged in padded LDS; per-thread
// sliding-window sums (O(1)/output); output transposed through LDS for
// coalesced global stores.

constexpr int T        = 8192;
constexpr int W        = 64;
constexpr int OUTW     = T - W + 1;   // 8129
constexpr int NTHREADS = 256;
constexpr int CHUNK    = 32;          // outputs per thread (256*32 = 8192 >= 8129)

// +1 float of pad per 32 elements: rotates bank index by (k>>5) so the
// per-thread stride-32 access patterns below are conflict-free.
__device__ __forceinline__ int padidx(int k) { return k + (k >> 5); }

__global__ __launch_bounds__(NTHREADS)
void MovingStandardDeviation_23682449670506_kernel(const float* __restrict__ x,
                                                   float* __restrict__ out) {
    __shared__ float lds[T + (T >> 5)];  // 8448 floats = 33 KiB
    const int t = threadIdx.x;
    const long long b = blockIdx.x;
    const float* row = x + b * (long long)T;

    // ---- Stage row into LDS, coalesced float4 loads. k%32 in {0..28} so the
    // 4 destination floats share one pad group (contiguous in LDS).
    #pragma unroll
    for (int i = 0; i < 8; ++i) {
        const int k = 4 * (t + i * NTHREADS);
        const float4 v = *reinterpret_cast<const float4*>(row + k);
        const int a = padidx(k);
        lds[a + 0] = v.x;
        lds[a + 1] = v.y;
        lds[a + 2] = v.z;
        lds[a + 3] = v.w;
    }
    __syncthreads();

    // ---- Sliding-window sums; each thread owns outputs [j0, j0+CHUNK).
    const int j0 = t * CHUNK;
    float res[CHUNK];                    // only compile-time-const indexed
    float s1 = 0.f, s2 = 0.f;

    #pragma unroll
    for (int m = 0; m < W; ++m) {
        int k = j0 + m;                  // up to 8223 for t=255: clamp (masked later)
        k = (k < T) ? k : (T - 1);
        const float v = lds[padidx(k)];
        s1 += v;
        s2 += v * v;
    }

    const float invw = 1.0f / (float)W;
    {
        const float mean = s1 * invw;
        const float var  = fmaxf(fmaf(-mean, mean, s2 * invw), 0.f);
        res[0] = sqrtf(var);
    }

    #pragma unroll
    for (int jj = 1; jj < CHUNK; ++jj) {
        const int j = j0 + jj;
        int kin = j + W - 1;             // clamp OOB tail reads (results masked)
        kin = (kin < T) ? kin : (T - 1);
        const int kout = j - 1;
        const float xin  = lds[padidx(kin)];
        const float xout = lds[padidx(kout)];
        s1 += xin - xout;
        s2 += xin * xin - xout * xout;
        const float mean = s1 * invw;
        const float var  = fmaxf(fmaf(-mean, mean, s2 * invw), 0.f);
        res[jj] = sqrtf(var);
    }
    __syncthreads();

    // ---- Transpose results through LDS (reuse buffer) for coalesced stores.
    #pragma unroll
    for (int jj = 0; jj < CHUNK; ++jj) {
        const int j = j0 + jj;
        if (j < OUTW) lds[padidx(j)] = res[jj];
    }
    __syncthreads();

    float* orow = out + b * (long long)OUTW;
    #pragma unroll
    for (int i = 0; i < CHUNK; ++i) {
        const int j = i * NTHREADS + t;  // lane-consecutive: coalesced
        if (j < OUTW) orow[j] = lds[padidx(j)];
    }
}

extern "C" void kernel_launch(void* const* d_in, const int* in_sizes, int n_in,
                              void* d_out, int out_size, void* d_ws, size_t ws_size,
                              hipStream_t stream) {
    const float* x = (const float*)d_in[0];
    float* out = (float*)d_out;
    const int B = in_sizes[0] / T;  // 4096
    MovingStandardDeviation_23682449670506_kernel<<<B, NTHREADS, 0, stream>>>(x, out);
}

// Round 3
// 46.505 us; speedup vs baseline: 1.5648x; 1.5648x over previous
//
#include <hip/hip_runtime.h>
#include <math.h>

// Rolling population std, window W=64, per row of x[B=4096][T=8192] fp32.
// One 256-thread block per row. Row staged in a 32 KiB XOR-swizzled LDS
// buffer (exactly 5 blocks/CU); all LDS traffic is ds_read_b128 /
// ds_write_b128; per-thread sliding-window sums give O(1) work per output;
// results round-trip through the same LDS buffer for coalesced stores.
//
// Swizzle (T2 / G4 pattern, dword units): d ^= ((d>>5)&7)<<2  — i.e. XOR
// dword-bits 2-4 with dword-bits 5-7. Same involution on write and read.

constexpr int T     = 8192;
constexpr int W     = 64;
constexpr int OUTW  = T - W + 1;   // 8129
constexpr int NT    = 256;
constexpr int CHUNK = 32;          // outputs per thread

__global__ __launch_bounds__(NT, 5)
void MovingStandardDeviation_23682449670506_kernel(const float* __restrict__ x,
                                                   float* __restrict__ out) {
    __shared__ float lds[T];                 // 32768 B exactly
    const int t = threadIdx.x;
    const size_t b = blockIdx.x;
    const float* rowp = x + b * (size_t)T;

    // ---- Stage row into LDS: 8 x (global float4 load -> swizzled b128 write).
    // d = 4t + 1024 i; row = (t>>3)&7 (i-independent) -> base XOR once.
    {
        const int srow = (t >> 3) & 7;
        const int sb = (4 * t) ^ (srow << 2);
        #pragma unroll
        for (int i = 0; i < 8; ++i) {
            const float4 v = *reinterpret_cast<const float4*>(rowp + 4 * t + 1024 * i);
            *reinterpret_cast<float4*>(lds + sb + 1024 * i) = v;
        }
    }
    __syncthreads();

    // ---- Compute. Thread t owns outputs j0..j0+31, needs inputs j0..j0+95
    // as 3 groups of 8 float4s. Group bases clamped to 8160 so reads stay
    // in-bounds for t>=254 (those results are masked at store).
    const int j0  = t * CHUNK;
    const int bk0 = j0;                       // <= 8160, never clamped
    const int bk1 = min(j0 + 32, T - 32);
    const int bk2 = min(j0 + 64, T - 32);

    float4 q[8];                              // kept: x[j0..j0+31] (xout source)
    {
        const int r0 = (bk0 >> 5) & 7;
        const int A0 = bk0 + (r0 << 2);
        #pragma unroll
        for (int c = 0; c < 8; ++c)
            q[c] = *reinterpret_cast<const float4*>(lds + (A0 ^ (c << 2)));
    }

    float s1, s2;
    {
        float a0 = 0.f, a1 = 0.f, a2 = 0.f, a3 = 0.f;
        float b0 = 0.f, b1 = 0.f, b2 = 0.f, b3 = 0.f;
        #pragma unroll
        for (int c = 0; c < 8; ++c) {
            a0 += q[c].x; b0 = fmaf(q[c].x, q[c].x, b0);
            a1 += q[c].y; b1 = fmaf(q[c].y, q[c].y, b1);
            a2 += q[c].z; b2 = fmaf(q[c].z, q[c].z, b2);
            a3 += q[c].w; b3 = fmaf(q[c].w, q[c].w, b3);
        }
        const int r1 = (bk1 >> 5) & 7;
        const int A1 = bk1 + (r1 << 2);
        #pragma unroll
        for (int c = 0; c < 8; ++c) {
            const float4 v = *reinterpret_cast<const float4*>(lds + (A1 ^ (c << 2)));
            a0 += v.x; b0 = fmaf(v.x, v.x, b0);
            a1 += v.y; b1 = fmaf(v.y, v.y, b1);
            a2 += v.z; b2 = fmaf(v.z, v.z, b2);
            a3 += v.w; b3 = fmaf(v.w, v.w, b3);
        }
        s1 = (a0 + a1) + (a2 + a3);
        s2 = (b0 + b1) + (b2 + b3);
    }

    float res[CHUNK];                         // compile-time-const indexed only
    const float invw = 1.0f / (float)W;
    {
        const float mean = s1 * invw;
        res[0] = sqrtf(fmaxf(fmaf(-mean, mean, s2 * invw), 0.f));
    }
    {
        const int r2 = (bk2 >> 5) & 7;
        const int A2 = bk2 + (r2 << 2);
        #pragma unroll
        for (int c = 0; c < 8; ++c) {
            const float4 vin = *reinterpret_cast<const float4*>(lds + (A2 ^ (c << 2)));
            #pragma unroll
            for (int e = 0; e < 4; ++e) {
                const int jj = 4 * c + e + 1;          // 1..32
                if (jj < CHUNK) {
                    const float xin  = (e == 0) ? vin.x : (e == 1) ? vin.y
                                     : (e == 2) ? vin.z : vin.w;
                    const int p = jj - 1;              // 0..30
                    const float4 qq = q[p >> 2];
                    const float xout = ((p & 3) == 0) ? qq.x : ((p & 3) == 1) ? qq.y
                                     : ((p & 3) == 2) ? qq.z : qq.w;
                    const float d = xin - xout;
                    s1 += d;
                    s2 = fmaf(d, xin + xout, s2);
                    const float mean = s1 * invw;
                    res[jj] = sqrtf(fmaxf(fmaf(-mean, mean, s2 * invw), 0.f));
                }
            }
        }
    }
    __syncthreads();

    // ---- Transpose: res -> own j0 region of LDS (float offset 32*t),
    // swizzled b128 writes. swz(32t+4c) = (32t + ((t&7)<<2)) ^ (c<<2).
    {
        const int A = 32 * t + ((t & 7) << 2);
        #pragma unroll
        for (int c = 0; c < 8; ++c) {
            const float4 v = make_float4(res[4 * c], res[4 * c + 1],
                                         res[4 * c + 2], res[4 * c + 3]);
            *reinterpret_cast<float4*>(lds + (A ^ (c << 2))) = v;
        }
    }
    __syncthreads();

    // ---- Coalesced scalar stores. d = t + 256 i; row = (t>>5)&7 const.
    {
        const int srow = (t >> 5) & 7;
        const int base = t ^ (srow << 2);
        float* orow = out + b * (size_t)OUTW;
        #pragma unroll
        for (int i = 0; i < 32; ++i) {
            const int j = t + 256 * i;
            const float f = lds[base + 256 * i];
            if (j < OUTW) orow[j] = f;
        }
    }
}

extern "C" void kernel_launch(void* const* d_in, const int* in_sizes, int n_in,
                              void* d_out, int out_size, void* d_ws, size_t ws_size,
                              hipStream_t stream) {
    const float* x = (const float*)d_in[0];
    float* out = (float*)d_out;
    const int B = in_sizes[0] / T;  // 4096
    MovingStandardDeviation_23682449670506_kernel<<<B, NT, 0, stream>>>(x, out);
}